// Round 7
// baseline (429.583 us; speedup 1.0000x reference)
//
#include <hip/hip_runtime.h>
#include <hip/hip_bf16.h>

typedef __bf16 bf16_t;
typedef __bf16 bf16x4 __attribute__((ext_vector_type(4)));
typedef __bf16 bf16x8 __attribute__((ext_vector_type(8)));
typedef float f32x4 __attribute__((ext_vector_type(4)));

#define AS1(p) ((const __attribute__((address_space(1))) void*)(p))
#define AS3(p) ((__attribute__((address_space(3))) void*)(p))

__device__ __forceinline__ f32x4 mfma16(bf16x8 a, bf16x8 b, f32x4 c) {
  return __builtin_amdgcn_mfma_f32_16x16x32_bf16(a, b, c, 0, 0, 0);
}

__global__ void cvt_f32_to_bf16(const float* __restrict__ in, bf16_t* __restrict__ out, int n) {
  int i = (blockIdx.x * 256 + threadIdx.x) * 4;
  if (i >= n) return;
  float4 v = *(const float4*)(in + i);
  bf16x4 o = {(bf16_t)v.x, (bf16_t)v.y, (bf16_t)v.z, (bf16_t)v.w};
  *(bf16x4*)(out + i) = o;
}

// Wt[n*K + k] = (bf16) W[k*N + n]
__global__ void transpose_cvt(const float* __restrict__ W, bf16_t* __restrict__ Wt,
                              int K, int N) {
  int idx = blockIdx.x * 256 + threadIdx.x;
  if (idx >= K * N) return;
  int n = idx / K, k = idx - n * K;
  Wt[idx] = (bf16_t)W[(size_t)k * N + n];
}

// C[M,N] = A[M,K] @ Bt[N,K]^T + bias ; 128x128 tile, BK=32, 4 waves (2x2 of 64x64).
// bf16-output variant (intermediates).
__global__ __launch_bounds__(256, 2)
void gemm_nt_bias_b16(const bf16_t* __restrict__ A, const bf16_t* __restrict__ Bt,
                      const float* __restrict__ bias, bf16_t* __restrict__ C,
                      int M, int N, int K) {
  __shared__ __align__(16) bf16_t As[128 * 32];
  __shared__ __align__(16) bf16_t Bs[128 * 32];
  const int tid = threadIdx.x;
  const int w = tid >> 6, l = tid & 63;
  const int l15 = l & 15, q = l >> 4;
  const int m0 = blockIdx.x * 128, n0 = blockIdx.y * 128;
  const int mw = (w >> 1) * 64, nw = (w & 1) * 64;
  f32x4 acc[4][4] = {};
  const int kb = (l & 3) * 8;
  int rA[2], rB[2];
#pragma unroll
  for (int i = 0; i < 2; ++i) {
    int row = (i * 4 + w) * 16 + (l >> 2);
    rA[i] = m0 + row;
    int rb = n0 + row; if (rb >= N) rb = N - 1;
    rB[i] = rb;
  }
  for (int k0 = 0; k0 < K; k0 += 32) {
#pragma unroll
    for (int i = 0; i < 2; ++i) {
      int sg = i * 4 + w;
      __builtin_amdgcn_global_load_lds(AS1(A + (size_t)rA[i] * K + k0 + kb),
                                       AS3(As + sg * 512), 16, 0, 0);
      __builtin_amdgcn_global_load_lds(AS1(Bt + (size_t)rB[i] * K + k0 + kb),
                                       AS3(Bs + sg * 512), 16, 0, 0);
    }
    __syncthreads();
    bf16x8 af[4], bfr[4];
#pragma unroll
    for (int mi = 0; mi < 4; ++mi)
      af[mi] = *(const bf16x8*)(As + (mw + mi * 16 + l15) * 32 + q * 8);
#pragma unroll
    for (int ni = 0; ni < 4; ++ni)
      bfr[ni] = *(const bf16x8*)(Bs + (nw + ni * 16 + l15) * 32 + q * 8);
#pragma unroll
    for (int mi = 0; mi < 4; ++mi)
#pragma unroll
      for (int ni = 0; ni < 4; ++ni)
        acc[mi][ni] = mfma16(af[mi], bfr[ni], acc[mi][ni]);
    __syncthreads();
  }
#pragma unroll
  for (int ni = 0; ni < 4; ++ni) {
    int col = n0 + nw + ni * 16 + l15;
    if (col >= N) continue;
    float bv = bias[col];
#pragma unroll
    for (int mi = 0; mi < 4; ++mi)
#pragma unroll
      for (int r = 0; r < 4; ++r) {
        int row = m0 + mw + mi * 16 + q * 4 + r;
        C[(size_t)row * N + col] = (bf16_t)(acc[mi][ni][r] + bv);
      }
  }
}

// fp32-output variant (final O-projection; d_out is fp32 per reference).
__global__ __launch_bounds__(256, 2)
void gemm_nt_bias_f32(const bf16_t* __restrict__ A, const bf16_t* __restrict__ Bt,
                      const float* __restrict__ bias, float* __restrict__ C,
                      int M, int N, int K) {
  __shared__ __align__(16) bf16_t As[128 * 32];
  __shared__ __align__(16) bf16_t Bs[128 * 32];
  const int tid = threadIdx.x;
  const int w = tid >> 6, l = tid & 63;
  const int l15 = l & 15, q = l >> 4;
  const int m0 = blockIdx.x * 128, n0 = blockIdx.y * 128;
  const int mw = (w >> 1) * 64, nw = (w & 1) * 64;
  f32x4 acc[4][4] = {};
  const int kb = (l & 3) * 8;
  int rA[2], rB[2];
#pragma unroll
  for (int i = 0; i < 2; ++i) {
    int row = (i * 4 + w) * 16 + (l >> 2);
    rA[i] = m0 + row;
    int rb = n0 + row; if (rb >= N) rb = N - 1;
    rB[i] = rb;
  }
  for (int k0 = 0; k0 < K; k0 += 32) {
#pragma unroll
    for (int i = 0; i < 2; ++i) {
      int sg = i * 4 + w;
      __builtin_amdgcn_global_load_lds(AS1(A + (size_t)rA[i] * K + k0 + kb),
                                       AS3(As + sg * 512), 16, 0, 0);
      __builtin_amdgcn_global_load_lds(AS1(Bt + (size_t)rB[i] * K + k0 + kb),
                                       AS3(Bs + sg * 512), 16, 0, 0);
    }
    __syncthreads();
    bf16x8 af[4], bfr[4];
#pragma unroll
    for (int mi = 0; mi < 4; ++mi)
      af[mi] = *(const bf16x8*)(As + (mw + mi * 16 + l15) * 32 + q * 8);
#pragma unroll
    for (int ni = 0; ni < 4; ++ni)
      bfr[ni] = *(const bf16x8*)(Bs + (nw + ni * 16 + l15) * 32 + q * 8);
#pragma unroll
    for (int mi = 0; mi < 4; ++mi)
#pragma unroll
      for (int ni = 0; ni < 4; ++ni)
        acc[mi][ni] = mfma16(af[mi], bfr[ni], acc[mi][ni]);
    __syncthreads();
  }
#pragma unroll
  for (int ni = 0; ni < 4; ++ni) {
    int col = n0 + nw + ni * 16 + l15;
    if (col >= N) continue;
    float bv = bias[col];
#pragma unroll
    for (int mi = 0; mi < 4; ++mi)
#pragma unroll
      for (int r = 0; r < 4; ++r) {
        int row = m0 + mw + mi * 16 + q * 4 + r;
        C[(size_t)row * N + col] = acc[mi][ni][r] + bv;
      }
  }
}

// Flash-style causal MQA. Block = (b, h, 64-row Q tile), 4 waves; K-tile = 64.
#define LDK 72
__global__ __launch_bounds__(256, 2)
void mqa_attn(const bf16_t* __restrict__ Qb, const bf16_t* __restrict__ Kb,
              const bf16_t* __restrict__ Vb, bf16_t* __restrict__ AO) {
  const int S = 2048, Dh = 64, Dm = 1024;
  __shared__ __align__(16) bf16_t Ks[64 * LDK];
  __shared__ __align__(16) bf16_t Vt[64 * LDK];
  __shared__ __align__(16) bf16_t Ps[64 * LDK];
  const int qt = blockIdx.x, h = blockIdx.y, b = blockIdx.z;
  const int tid = threadIdx.x, w = tid >> 6, l = tid & 63;
  const int l15 = l & 15, q = l >> 4;

  const bf16_t* qrow = Qb + (size_t)(b * S + qt * 64 + w * 16 + l15) * Dm + h * Dh;
  bf16x8 qf0 = *(const bf16x8*)(qrow + q * 8);
  bf16x8 qf1 = *(const bf16x8*)(qrow + 32 + q * 8);

  float m_r[4] = {-1e30f, -1e30f, -1e30f, -1e30f};
  float l_r[4] = {0.f, 0.f, 0.f, 0.f};
  f32x4 o[4] = {};

  const int kr = tid >> 2, kc = (tid & 3) * 16;
  const int vd = tid & 63, vk0 = (tid >> 6) * 16;

  for (int kt = 0; kt <= qt; ++kt) {
    __syncthreads();
    {
      const bf16_t* gk = Kb + (size_t)(b * S + kt * 64 + kr) * Dh + kc;
      bf16x8 kv0 = *(const bf16x8*)gk;
      bf16x8 kv1 = *(const bf16x8*)(gk + 8);
      const bf16_t* gv = Vb + (size_t)(b * S + kt * 64 + vk0) * Dh + vd;
      bf16x8 tv0, tv1;
#pragma unroll
      for (int j = 0; j < 8; ++j) {
        tv0[j] = gv[(size_t)j * Dh];
        tv1[j] = gv[(size_t)(j + 8) * Dh];
      }
      *(bf16x8*)(Ks + kr * LDK + kc) = kv0;
      *(bf16x8*)(Ks + kr * LDK + kc + 8) = kv1;
      *(bf16x8*)(Vt + vd * LDK + vk0) = tv0;
      *(bf16x8*)(Vt + vd * LDK + vk0 + 8) = tv1;
    }
    __syncthreads();

    f32x4 s[4];
#pragma unroll
    for (int ni = 0; ni < 4; ++ni) {
      bf16x8 b0 = *(const bf16x8*)(Ks + (ni * 16 + l15) * LDK + q * 8);
      bf16x8 b1 = *(const bf16x8*)(Ks + (ni * 16 + l15) * LDK + 32 + q * 8);
      f32x4 t = {0.f, 0.f, 0.f, 0.f};
      t = mfma16(qf0, b0, t);
      t = mfma16(qf1, b1, t);
      s[ni] = t;
    }

    const int rowg = qt * 64 + w * 16 + q * 4;
    const bool diag = (kt == qt);
#pragma unroll
    for (int ni = 0; ni < 4; ++ni) {
      int colg = kt * 64 + ni * 16 + l15;
#pragma unroll
      for (int r = 0; r < 4; ++r) {
        float v = s[ni][r] * 0.125f;
        if (diag && colg > rowg + r) v = -1e30f;
        s[ni][r] = v;
      }
    }

    float mx[4], rs[4];
#pragma unroll
    for (int r = 0; r < 4; ++r)
      mx[r] = fmaxf(fmaxf(s[0][r], s[1][r]), fmaxf(s[2][r], s[3][r]));
#pragma unroll
    for (int off = 8; off > 0; off >>= 1)
#pragma unroll
      for (int r = 0; r < 4; ++r)
        mx[r] = fmaxf(mx[r], __shfl_xor(mx[r], off, 16));
#pragma unroll
    for (int r = 0; r < 4; ++r) {
      float mn = fmaxf(m_r[r], mx[r]);
      float al = __expf(m_r[r] - mn);
      m_r[r] = mn;
      l_r[r] *= al;
#pragma unroll
      for (int ni = 0; ni < 4; ++ni) o[ni][r] *= al;
      rs[r] = 0.f;
    }
#pragma unroll
    for (int ni = 0; ni < 4; ++ni)
#pragma unroll
      for (int r = 0; r < 4; ++r) {
        float p = __expf(s[ni][r] - m_r[r]);
        rs[r] += p;
        Ps[(w * 16 + q * 4 + r) * LDK + ni * 16 + l15] = (bf16_t)p;
      }
#pragma unroll
    for (int off = 8; off > 0; off >>= 1)
#pragma unroll
      for (int r = 0; r < 4; ++r) rs[r] += __shfl_xor(rs[r], off, 16);
#pragma unroll
    for (int r = 0; r < 4; ++r) l_r[r] += rs[r];

    __syncthreads();

    bf16x8 a0 = *(const bf16x8*)(Ps + (w * 16 + l15) * LDK + q * 8);
    bf16x8 a1 = *(const bf16x8*)(Ps + (w * 16 + l15) * LDK + 32 + q * 8);
#pragma unroll
    for (int ni = 0; ni < 4; ++ni) {
      bf16x8 v0 = *(const bf16x8*)(Vt + (ni * 16 + l15) * LDK + q * 8);
      bf16x8 v1 = *(const bf16x8*)(Vt + (ni * 16 + l15) * LDK + 32 + q * 8);
      o[ni] = mfma16(a0, v0, o[ni]);
      o[ni] = mfma16(a1, v1, o[ni]);
    }
  }

  float inv[4];
#pragma unroll
  for (int r = 0; r < 4; ++r) inv[r] = 1.f / l_r[r];
#pragma unroll
  for (int ni = 0; ni < 4; ++ni)
#pragma unroll
    for (int r = 0; r < 4; ++r)
      AO[(size_t)(b * S + qt * 64 + w * 16 + q * 4 + r) * Dm + h * Dh + ni * 16 + l15] =
          (bf16_t)(o[ni][r] * inv[r]);
}

extern "C" void kernel_launch(void* const* d_in, const int* in_sizes, int n_in,
                              void* d_out, int out_size, void* d_ws, size_t ws_size,
                              hipStream_t stream) {
  (void)in_sizes; (void)n_in; (void)out_size; (void)ws_size;
  const int BS = 8192;  // B*S
  const float* x  = (const float*)d_in[0];
  const float* Wq = (const float*)d_in[1];
  const float* bq = (const float*)d_in[2];
  const float* Wk = (const float*)d_in[3];
  const float* bk = (const float*)d_in[4];
  const float* Wv = (const float*)d_in[5];
  const float* bv = (const float*)d_in[6];
  const float* Wo = (const float*)d_in[7];
  const float* bo = (const float*)d_in[8];
  float* out = (float*)d_out;  // reference output dtype is fp32

  bf16_t* p = (bf16_t*)d_ws;
  bf16_t* WqT = p; p += 1024 * 1024;
  bf16_t* WkT = p; p += 64 * 1024;
  bf16_t* WvT = p; p += 64 * 1024;
  bf16_t* WoT = p; p += 1024 * 1024;
  bf16_t* xb  = p; p += (size_t)BS * 1024;
  bf16_t* Qb  = p; p += (size_t)BS * 1024;
  bf16_t* Kb  = p; p += (size_t)BS * 64;
  bf16_t* Vb  = p; p += (size_t)BS * 64;
  bf16_t* AO  = xb;  // x dead after projections

  cvt_f32_to_bf16<<<(BS * 1024 / 4 + 255) / 256, 256, 0, stream>>>(x, xb, BS * 1024);
  transpose_cvt<<<(1024 * 1024 + 255) / 256, 256, 0, stream>>>(Wq, WqT, 1024, 1024);
  transpose_cvt<<<(64 * 1024 + 255) / 256, 256, 0, stream>>>(Wk, WkT, 1024, 64);
  transpose_cvt<<<(64 * 1024 + 255) / 256, 256, 0, stream>>>(Wv, WvT, 1024, 64);
  transpose_cvt<<<(1024 * 1024 + 255) / 256, 256, 0, stream>>>(Wo, WoT, 1024, 1024);

  gemm_nt_bias_b16<<<dim3(BS / 128, 8), 256, 0, stream>>>(xb, WqT, bq, Qb, BS, 1024, 1024);
  gemm_nt_bias_b16<<<dim3(BS / 128, 1), 256, 0, stream>>>(xb, WkT, bk, Kb, BS, 64, 1024);
  gemm_nt_bias_b16<<<dim3(BS / 128, 1), 256, 0, stream>>>(xb, WvT, bv, Vb, BS, 64, 1024);

  mqa_attn<<<dim3(32, 16, 4), 256, 0, stream>>>(Qb, Kb, Vb, AO);

  gemm_nt_bias_f32<<<dim3(BS / 128, 8), 256, 0, stream>>>(AO, WoT, bo, out, BS, 1024, 1024);
}